// Round 1
// baseline (26.524 us; speedup 1.0000x reference)
//
#include <hip/hip_runtime.h>
#include <math.h>

typedef _Float16 h2 __attribute__((ext_vector_type(2)));
typedef __fp16  hh2 __attribute__((ext_vector_type(2)));

constexpr int Lc = 128;
constexpr int Sc = 8;

// ---- LDS dword map (pair-interleaved SoA; all vector reads are b64 at
//      lane-stride 8B = 2-way bank aliasing = conflict-free) ----
// ABD  : groups g=0..11  at lds[g*256 + li*2 + {0,1}]
//        A = groups 0..3 (dwords k=0..7), B = 4..7, D = 8..11
// F    : groups fg=0..3  at lds[3072 + fg*256 + li*2 + {0,1}]
//        fg0=(uxs,uys) fg1=(vxs,vys) fg2=(vzs,lxc) fg3=(lyc,lzc)
// WQP  : float at lds[4096 + li]       ( wq/(8wq+1e-6) )
// PB   : lds[4224 + pt*8 + k], pt=0,1  ( pk(points@W1[:3]+b1) per block point )
constexpr int F_OFF  = 3072;
constexpr int WQ_OFF = 4096;
constexpr int PB_OFF = 4224;
constexpr int LDS_DW = 4240;

static __device__ __forceinline__ h2 pk(float a, float b) {
    return __builtin_bit_cast(h2, __builtin_amdgcn_cvt_pkrtz(a, b));
}
static __device__ __forceinline__ h2 u2h(unsigned u) {
    return __builtin_bit_cast(h2, u);
}
static __device__ __forceinline__ unsigned h2u(h2 v) {
    return __builtin_bit_cast(unsigned, v);
}
static __device__ __forceinline__ float fdot2f(h2 a, h2 b, float c) {
#if __has_builtin(__builtin_amdgcn_fdot2)
    return __builtin_amdgcn_fdot2(__builtin_bit_cast(hh2, a),
                                  __builtin_bit_cast(hh2, b), c, false);
#else
    return c + (float)a.x * (float)b.x + (float)a.y * (float)b.y;
#endif
}
static __device__ __forceinline__ float fast_exp2(float x) {
#if __has_builtin(__builtin_amdgcn_exp2f)
    return __builtin_amdgcn_exp2f(x);
#else
    return exp2f(x);
#endif
}

__global__ __launch_bounds__(256, 4) void vis_fused(
    const float* __restrict__ points,
    const float* __restrict__ normals,
    const float* __restrict__ root_rot,
    const float* __restrict__ lobes,
    const float* __restrict__ lambdas,
    const float* __restrict__ rtheta,
    const float* __restrict__ W1,
    const float* __restrict__ b1,
    const float* __restrict__ W2,
    const float* __restrict__ b2,
    float* __restrict__ out, int N)
{
    __shared__ __align__(16) unsigned lds[LDS_DW];
    const int tid = threadIdx.x;
    const int li  = tid & (Lc - 1);

    // ================= phase 1: per-block precompute into LDS =================
    // Both wave-pairs run the shared prolog for the same li; tid<128 emits
    // ABD dwords k=0..3 (+F,+WQP), tid>=128 emits k=4..7. Deterministic pure
    // recompute per block — no inter-block dependency, no second kernel.
    {
        float lx = lobes[li*3+0], ly = lobes[li*3+1], lz = lobes[li*3+2];
        float inv = 1.0f / (sqrtf(lx*lx + ly*ly + lz*lz) + 1e-6f);
        lx *= inv; ly *= inv; lz *= inv;

        float ux = -ly, uy = lx;                       // cross(z,l)
        inv = 1.0f / (sqrtf(ux*ux + uy*uy) + 1e-6f);
        ux *= inv; uy *= inv;

        float vx = -lz*uy, vy = lz*ux, vz = lx*uy - ly*ux;  // cross(l,U)
        inv = 1.0f / (sqrtf(vx*vx + vy*vy + vz*vz) + 1e-6f);
        vx *= inv; vy *= inv; vz *= inv;

        float sharp = lambdas[li];
        float cp = fmaxf(1.0f - 1.0f/sharp, 0.5f);
        float sp = sqrtf(fmaxf(1.0f - cp*cp, 0.0f));

        float uxs = ux*sp, uys = uy*sp;               // uzs == 0
        float vxs = vx*sp, vys = vy*sp, vzs = vz*sp;
        float lxc = lx*cp, lyc = ly*cp, lzc = lz*cp;

        const float r0 = root_rot[0], r1 = root_rot[1], r2 = root_rot[2];
        const float r3 = root_rot[3], r4 = root_rot[4], r5 = root_rot[5];
        const float r6 = root_rot[6], r7 = root_rot[7], r8 = root_rot[8];

        float Ur0 = -(uxs*r0 + uys*r3);
        float Ur1 = -(uxs*r1 + uys*r4);
        float Ur2 = -(uxs*r2 + uys*r5);
        float Vr0 = -(vxs*r0 + vys*r3 + vzs*r6);
        float Vr1 = -(vxs*r1 + vys*r4 + vzs*r7);
        float Vr2 = -(vxs*r2 + vys*r5 + vzs*r8);
        float Lr0 = -(lxc*r0 + lyc*r3 + lzc*r6);
        float Lr1 = -(lxc*r1 + lyc*r4 + lzc*r7);
        float Lr2 = -(lxc*r2 + lyc*r5 + lzc*r8);

        const int k0 = (tid < 128) ? 0 : 4;
        unsigned av[4], bv[4], dv[4];
        #pragma unroll
        for (int j = 0; j < 4; ++j) {
            int h0 = 2*(k0 + j), h1 = h0 + 1;
            float a0  = Ur0*W1[48+h0] + Ur1*W1[64+h0] + Ur2*W1[80+h0];
            float a1  = Ur0*W1[48+h1] + Ur1*W1[64+h1] + Ur2*W1[80+h1];
            float bb0 = Vr0*W1[48+h0] + Vr1*W1[64+h0] + Vr2*W1[80+h0];
            float bb1 = Vr0*W1[48+h1] + Vr1*W1[64+h1] + Vr2*W1[80+h1];
            float d0  = Lr0*W1[48+h0] + Lr1*W1[64+h0] + Lr2*W1[80+h0];
            float d1  = Lr0*W1[48+h1] + Lr1*W1[64+h1] + Lr2*W1[80+h1];
            av[j] = h2u(pk(a0, a1));
            bv[j] = h2u(pk(bb0, bb1));
            dv[j] = h2u(pk(d0, d1));
        }
        // b64 writes, lane-stride 8B (2-way = free)
        #pragma unroll
        for (int j = 0; j < 4; j += 2) {
            int g = (k0 + j) >> 1;
            *(uint2*)(lds + (0*4 + g)*256 + li*2) = (uint2){av[j], av[j+1]};
            *(uint2*)(lds + (1*4 + g)*256 + li*2) = (uint2){bv[j], bv[j+1]};
            *(uint2*)(lds + (2*4 + g)*256 + li*2) = (uint2){dv[j], dv[j+1]};
        }

        float* wf = (float*)lds;
        if (tid < 128) {
            *(float2*)(wf + F_OFF + 0*256 + li*2) = (float2){uxs, uys};
            *(float2*)(wf + F_OFF + 1*256 + li*2) = (float2){vxs, vys};
            *(float2*)(wf + F_OFF + 2*256 + li*2) = (float2){vzs, lxc};
            *(float2*)(wf + F_OFF + 3*256 + li*2) = (float2){lyc, lzc};
            float wq = __expf(sharp * (cp - 1.0f));
            wf[WQ_OFF + li] = wq / (8.0f * wq + 1e-6f);
        } else if (tid < 130) {
            // pb for this block's two points (exec-masked: 2 lanes, ~70cy)
            int p = (blockIdx.x << 1) + (tid - 128);
            if (p < N) {
                float px = points[3*p], py = points[3*p+1], pz = points[3*p+2];
                #pragma unroll
                for (int k = 0; k < 8; ++k) {
                    int h0 = 2*k, h1 = 2*k + 1;
                    float v0 = b1[h0] + px*W1[h0] + py*W1[16+h0] + pz*W1[32+h0];
                    float v1 = b1[h1] + px*W1[h1] + py*W1[16+h1] + pz*W1[32+h1];
                    lds[PB_OFF + (tid - 128)*8 + k] = h2u(pk(v0, v1));
                }
            }
        }
    }
    __syncthreads();

    // ================= phase 2: main visibility loop =================
    const int idx = blockIdx.x * 256 + tid;     // idx = n*128 + li
    if (idx >= N * Lc) return;
    const int n = (blockIdx.x << 1) + (tid >> 7);

    // per-lobe records: b64 LDS reads, 2-way = conflict-free
    uint2 t[12];
    #pragma unroll
    for (int g = 0; g < 12; ++g)
        t[g] = *(const uint2*)(lds + g*256 + li*2);
    const float* wf = (const float*)lds;
    float2 g0 = *(const float2*)(wf + F_OFF + 0*256 + li*2);
    float2 g1 = *(const float2*)(wf + F_OFF + 1*256 + li*2);
    float2 g2 = *(const float2*)(wf + F_OFF + 2*256 + li*2);
    float2 g3 = *(const float2*)(wf + F_OFF + 3*256 + li*2);
    float wqp = wf[WQ_OFF + li];

    // rtheta: 32 B/lane coalesced
    const float4 q0 = *reinterpret_cast<const float4*>(rtheta + (size_t)idx * Sc);
    const float4 q1 = *reinterpret_cast<const float4*>(rtheta + (size_t)idx * Sc + 4);
    float rs[Sc] = {q0.x, q0.y, q0.z, q0.w, q1.x, q1.y, q1.z, q1.w};

    // wave-uniform per-point data
    int nu = __builtin_amdgcn_readfirstlane(n);
    const float* nn = normals + 3*(size_t)nu;
    float nx = nn[0], ny = nn[1], nz = nn[2];
    const unsigned* pbp = lds + PB_OFF + (tid >> 7)*8;   // uniform addr → broadcast

    h2 A[8] = {u2h(t[0].x), u2h(t[0].y), u2h(t[1].x), u2h(t[1].y),
               u2h(t[2].x), u2h(t[2].y), u2h(t[3].x), u2h(t[3].y)};
    h2 B[8] = {u2h(t[4].x), u2h(t[4].y), u2h(t[5].x), u2h(t[5].y),
               u2h(t[6].x), u2h(t[6].y), u2h(t[7].x), u2h(t[7].y)};
    h2 G[8] = {u2h(pbp[0]) + u2h(t[8].x),  u2h(pbp[1]) + u2h(t[8].y),
               u2h(pbp[2]) + u2h(t[9].x),  u2h(pbp[3]) + u2h(t[9].y),
               u2h(pbp[4]) + u2h(t[10].x), u2h(pbp[5]) + u2h(t[10].y),
               u2h(pbp[6]) + u2h(t[11].x), u2h(pbp[7]) + u2h(t[11].y)};

    // W2/b2: tiny, uniform → scalar loads; 8 cvt_pkrtz per thread
    h2 W2h[8];
    #pragma unroll
    for (int k = 0; k < 8; ++k) W2h[k] = pk(W2[2*k], W2[2*k+1]);
    float b2c = -b2[0] * 1.44269504f;

    // ndot = ct*nU + st*nV + nL
    float nU = nx*g0.x + ny*g0.y;
    float nV = nx*g1.x + ny*g1.y + nz*g2.x;
    float nL = nx*g2.y + ny*g3.x + nz*g3.y;

    const h2 zero = {(_Float16)0.0f, (_Float16)0.0f};
    float svis = 0.0f;
    #pragma unroll
    for (int s = 0; s < Sc; ++s) {
        // angle in revolutions; v_sin/cos_f32 take revolutions
        float f  = fmaf(rs[s], 0.125f, (float)s * 0.125f);
        float st = __builtin_amdgcn_sinf(f);
        float ct = __builtin_amdgcn_cosf(f);
        float ndot = fmaf(ct, nU, fmaf(st, nV, nL));

        h2 ct2 = pk(ct, ct);
        h2 st2 = pk(st, st);

        float acc = 0.0f;
        #pragma unroll
        for (int k = 0; k < 8; ++k) {
            h2 hv = __builtin_elementwise_fma(ct2, A[k],
                     __builtin_elementwise_fma(st2, B[k], G[k]));
            hv = __builtin_elementwise_max(hv, zero);
            acc = fdot2f(hv, W2h[k], acc);
        }
        // sigmoid(acc + b2) = 1/(1 + 2^(-(acc+b2)*log2e))
        float e = fast_exp2(fmaf(acc, -1.44269504f, b2c));
        float pred = __builtin_amdgcn_rcpf(1.0f + e);
        svis += (ndot > 1e-6f) ? pred : 0.0f;
    }

    out[idx] = svis * wqp;
}

extern "C" void kernel_launch(void* const* d_in, const int* in_sizes, int n_in,
                              void* d_out, int out_size, void* d_ws, size_t ws_size,
                              hipStream_t stream) {
    const float* points  = (const float*)d_in[0];
    const float* normals = (const float*)d_in[1];
    const float* root_rot= (const float*)d_in[2];
    const float* lobes   = (const float*)d_in[3];
    const float* lambdas = (const float*)d_in[4];
    const float* rtheta  = (const float*)d_in[5];
    const float* W1      = (const float*)d_in[6];
    const float* b1      = (const float*)d_in[7];
    const float* W2      = (const float*)d_in[8];
    const float* b2      = (const float*)d_in[9];
    float* out = (float*)d_out;
    (void)d_ws; (void)ws_size;   // workspace no longer needed

    int N = in_sizes[0] / 3;
    int total = N * Lc;
    vis_fused<<<(total + 255) / 256, 256, 0, stream>>>(
        points, normals, root_rot, lobes, lambdas, rtheta,
        W1, b1, W2, b2, out, N);
}

// Round 2
// 26.366 us; speedup vs baseline: 1.0060x; 1.0060x over previous
//
#include <hip/hip_runtime.h>
#include <math.h>

typedef _Float16 h2 __attribute__((ext_vector_type(2)));
typedef __fp16  hh2 __attribute__((ext_vector_type(2)));

constexpr int Lc = 128;
constexpr int Sc = 8;
// ---- workspace dword map (SoA, coalesced 16B/lane reads) ----
// T[c][li]  c=0..5 : uint4 at dword c*512 + li*4   (A01,A23,B01,B23,D01,D23)
// F0[li]           : float4 at dword 3072 + li*4   (uxs,uys,vxs,vys)
// F1[li]           : float4 at dword 3584 + li*4   (vzs,lxc,lyc,lzc)
// WQP[li]          : float  at dword 4096 + li     ( wq/(8wq+1e-6) )
// W2H              : 8 dwords (half2) at 4224
// B2C              : 1 dword at 4232               ( -b2*log2e )
// PB[n]            : 8 dwords (half2) at 4352+8n
constexpr int F0_OFF = 3072;
constexpr int F1_OFF = 3584;
constexpr int WQ_OFF = 4096;
constexpr int W2_OFF = 4224;
constexpr int B2_OFF = 4232;
constexpr int PB_OFF = 4352;

static __device__ __forceinline__ h2 pk(float a, float b) {
    return __builtin_bit_cast(h2, __builtin_amdgcn_cvt_pkrtz(a, b));
}
static __device__ __forceinline__ h2 u2h(unsigned u) {
    return __builtin_bit_cast(h2, u);
}
static __device__ __forceinline__ unsigned h2u(h2 v) {
    return __builtin_bit_cast(unsigned, v);
}
static __device__ __forceinline__ float fdot2f(h2 a, h2 b, float c) {
#if __has_builtin(__builtin_amdgcn_fdot2)
    return __builtin_amdgcn_fdot2(__builtin_bit_cast(hh2, a),
                                  __builtin_bit_cast(hh2, b), c, false);
#else
    return c + (float)a.x * (float)b.x + (float)a.y * (float)b.y;
#endif
}
static __device__ __forceinline__ float fast_exp2(float x) {
#if __has_builtin(__builtin_amdgcn_exp2f)
    return __builtin_amdgcn_exp2f(x);
#else
    return exp2f(x);
#endif
}

__global__ __launch_bounds__(256) void precompute(
    const float* __restrict__ points,
    const float* __restrict__ root_rot,
    const float* __restrict__ lobes,
    const float* __restrict__ lambdas,
    const float* __restrict__ W1,
    const float* __restrict__ b1,
    const float* __restrict__ W2,
    const float* __restrict__ b2,
    unsigned* __restrict__ ws, int N)
{
    int g = blockIdx.x * 256 + threadIdx.x;

    // ---- per-point pb table: pk(points @ W1[:3] + b1) ----
    if (g < N) {
        float px = points[3*g], py = points[3*g+1], pz = points[3*g+2];
        unsigned* dst = ws + PB_OFF + 8*(size_t)g;
        #pragma unroll
        for (int k = 0; k < 8; ++k) {
            int h0 = 2*k, h1 = 2*k+1;
            float v0 = b1[h0] + px*W1[h0] + py*W1[16+h0] + pz*W1[32+h0];
            float v1 = b1[h1] + px*W1[h1] + py*W1[16+h1] + pz*W1[32+h1];
            dst[k] = h2u(pk(v0, v1));
        }
    }

    // ---- per-lobe SoA records ----
    if (g < Lc) {
        int li = g;
        float lx = lobes[li*3+0], ly = lobes[li*3+1], lz = lobes[li*3+2];
        float inv = 1.0f / (sqrtf(lx*lx + ly*ly + lz*lz) + 1e-6f);
        lx *= inv; ly *= inv; lz *= inv;

        float ux = -ly, uy = lx;                       // cross(z,l)
        inv = 1.0f / (sqrtf(ux*ux + uy*uy) + 1e-6f);
        ux *= inv; uy *= inv;

        float vx = -lz*uy, vy = lz*ux, vz = lx*uy - ly*ux;  // cross(l,U)
        inv = 1.0f / (sqrtf(vx*vx + vy*vy + vz*vz) + 1e-6f);
        vx *= inv; vy *= inv; vz *= inv;

        float sharp = lambdas[li];
        float cp = fmaxf(1.0f - 1.0f/sharp, 0.5f);
        float sp = sqrtf(fmaxf(1.0f - cp*cp, 0.0f));

        float uxs = ux*sp, uys = uy*sp;               // uzs == 0
        float vxs = vx*sp, vys = vy*sp, vzs = vz*sp;
        float lxc = lx*cp, lyc = ly*cp, lzc = lz*cp;

        const float r0 = root_rot[0], r1 = root_rot[1], r2 = root_rot[2];
        const float r3 = root_rot[3], r4 = root_rot[4], r5 = root_rot[5];
        const float r6 = root_rot[6], r7 = root_rot[7], r8 = root_rot[8];

        float Ur0 = -(uxs*r0 + uys*r3);
        float Ur1 = -(uxs*r1 + uys*r4);
        float Ur2 = -(uxs*r2 + uys*r5);
        float Vr0 = -(vxs*r0 + vys*r3 + vzs*r6);
        float Vr1 = -(vxs*r1 + vys*r4 + vzs*r7);
        float Vr2 = -(vxs*r2 + vys*r5 + vzs*r8);
        float Lr0 = -(lxc*r0 + lyc*r3 + lzc*r6);
        float Lr1 = -(lxc*r1 + lyc*r4 + lzc*r7);
        float Lr2 = -(lxc*r2 + lyc*r5 + lzc*r8);

        unsigned abd[24];
        #pragma unroll
        for (int k = 0; k < 8; ++k) {
            int h0 = 2*k, h1 = 2*k + 1;
            float a0 = Ur0*W1[48+h0] + Ur1*W1[64+h0] + Ur2*W1[80+h0];
            float a1 = Ur0*W1[48+h1] + Ur1*W1[64+h1] + Ur2*W1[80+h1];
            float bb0 = Vr0*W1[48+h0] + Vr1*W1[64+h0] + Vr2*W1[80+h0];
            float bb1 = Vr0*W1[48+h1] + Vr1*W1[64+h1] + Vr2*W1[80+h1];
            float d0 = Lr0*W1[48+h0] + Lr1*W1[64+h0] + Lr2*W1[80+h0];
            float d1 = Lr0*W1[48+h1] + Lr1*W1[64+h1] + Lr2*W1[80+h1];
            abd[k]      = h2u(pk(a0, a1));
            abd[8 + k]  = h2u(pk(bb0, bb1));
            abd[16 + k] = h2u(pk(d0, d1));
        }
        uint4* tv = (uint4*)ws;
        #pragma unroll
        for (int c = 0; c < 6; ++c)
            tv[c*128 + li] = *(const uint4*)(abd + 4*c);

        float* wf = (float*)ws;
        *(float4*)(wf + F0_OFF + 4*li) = (float4){uxs, uys, vxs, vys};
        *(float4*)(wf + F1_OFF + 4*li) = (float4){vzs, lxc, lyc, lzc};
        float wq = __expf(sharp * (cp - 1.0f));
        wf[WQ_OFF + li] = wq / (8.0f * wq + 1e-6f);

        if (li == 0) {
            #pragma unroll
            for (int k = 0; k < 8; ++k)
                ws[W2_OFF + k] = h2u(pk(W2[2*k], W2[2*k+1]));
            wf[B2_OFF] = -b2[0] * 1.44269504f;
        }
    }
}

__global__ __launch_bounds__(256, 4) void vis_main(
    const float* __restrict__ normals,  // N,3
    const float* __restrict__ rtheta,   // N,L,S
    const unsigned* __restrict__ ws,
    float* __restrict__ out, int N)
{
    int idx = blockIdx.x * 256 + threadIdx.x;
    if (idx >= N * Lc) return;
    int n  = idx >> 7;
    int li = idx & (Lc - 1);

    // ---- per-lobe SoA reads: 16B/lane, coalesced, L1/L2-hot ----
    const uint4* tv = (const uint4*)ws;
    uint4 a01 = tv[0*128 + li];
    uint4 a23 = tv[1*128 + li];
    uint4 bb01 = tv[2*128 + li];
    uint4 bb23 = tv[3*128 + li];
    uint4 d01 = tv[4*128 + li];
    uint4 d23 = tv[5*128 + li];
    const float* wf = (const float*)ws;
    float4 f0 = *(const float4*)(wf + F0_OFF + 4*li);
    float4 f1 = *(const float4*)(wf + F1_OFF + 4*li);
    float wqp = wf[WQ_OFF + li];

    // ---- rtheta: 32 B/lane coalesced ----
    const float4 q0 = *reinterpret_cast<const float4*>(rtheta + (size_t)idx * Sc);
    const float4 q1 = *reinterpret_cast<const float4*>(rtheta + (size_t)idx * Sc + 4);
    float rs[Sc] = {q0.x, q0.y, q0.z, q0.w, q1.x, q1.y, q1.z, q1.w};

    // ---- wave-uniform per-point data (scalar path) ----
    int nu = __builtin_amdgcn_readfirstlane(n);
    const float* nn = normals + 3*(size_t)nu;
    float nx = nn[0], ny = nn[1], nz = nn[2];
    const unsigned* pbp = ws + PB_OFF + 8*(size_t)nu;
    unsigned pb[8] = {pbp[0], pbp[1], pbp[2], pbp[3],
                      pbp[4], pbp[5], pbp[6], pbp[7]};

    h2 A[8] = {u2h(a01.x), u2h(a01.y), u2h(a01.z), u2h(a01.w),
               u2h(a23.x), u2h(a23.y), u2h(a23.z), u2h(a23.w)};
    h2 B[8] = {u2h(bb01.x), u2h(bb01.y), u2h(bb01.z), u2h(bb01.w),
               u2h(bb23.x), u2h(bb23.y), u2h(bb23.z), u2h(bb23.w)};
    h2 G[8] = {u2h(pb[0]) + u2h(d01.x), u2h(pb[1]) + u2h(d01.y),
               u2h(pb[2]) + u2h(d01.z), u2h(pb[3]) + u2h(d01.w),
               u2h(pb[4]) + u2h(d23.x), u2h(pb[5]) + u2h(d23.y),
               u2h(pb[6]) + u2h(d23.z), u2h(pb[7]) + u2h(d23.w)};
    h2 W2h[8] = {u2h(ws[W2_OFF+0]), u2h(ws[W2_OFF+1]),
                 u2h(ws[W2_OFF+2]), u2h(ws[W2_OFF+3]),
                 u2h(ws[W2_OFF+4]), u2h(ws[W2_OFF+5]),
                 u2h(ws[W2_OFF+6]), u2h(ws[W2_OFF+7])};
    float b2c = wf[B2_OFF];   // -b2*log2e

    // ndot = ct*nU + st*nV + nL
    float nU = nx*f0.x + ny*f0.y;
    float nV = nx*f0.z + ny*f0.w + nz*f1.x;
    float nL = nx*f1.y + ny*f1.z + nz*f1.w;

    const h2 zero = {(_Float16)0.0f, (_Float16)0.0f};
    float svis = 0.0f;
    // unroll 2 (NOT 8): full unroll needs ~130-140 live VGPRs against the
    // 128-VGPR cap from __launch_bounds__(256,4) -> spills/serialization.
    // 2-deep keeps ILP for latency hiding while staying well under the cap.
    #pragma unroll 2
    for (int s = 0; s < Sc; ++s) {
        // angle in revolutions; v_sin/cos_f32 take revolutions
        float f  = fmaf(rs[s], 0.125f, (float)s * 0.125f);
        float st = __builtin_amdgcn_sinf(f);
        float ct = __builtin_amdgcn_cosf(f);
        float ndot = fmaf(ct, nU, fmaf(st, nV, nL));

        h2 ct2 = pk(ct, ct);
        h2 st2 = pk(st, st);

        float acc = 0.0f;
        #pragma unroll
        for (int k = 0; k < 8; ++k) {
            h2 hv = __builtin_elementwise_fma(ct2, A[k],
                     __builtin_elementwise_fma(st2, B[k], G[k]));
            hv = __builtin_elementwise_max(hv, zero);
            acc = fdot2f(hv, W2h[k], acc);
        }
        // sigmoid(acc + b2) = 1/(1 + 2^(-(acc+b2)*log2e))
        float e = fast_exp2(fmaf(acc, -1.44269504f, b2c));
        float pred = __builtin_amdgcn_rcpf(1.0f + e);
        svis += (ndot > 1e-6f) ? pred : 0.0f;
    }

    out[idx] = svis * wqp;
}

extern "C" void kernel_launch(void* const* d_in, const int* in_sizes, int n_in,
                              void* d_out, int out_size, void* d_ws, size_t ws_size,
                              hipStream_t stream) {
    const float* points  = (const float*)d_in[0];
    const float* normals = (const float*)d_in[1];
    const float* root_rot= (const float*)d_in[2];
    const float* lobes   = (const float*)d_in[3];
    const float* lambdas = (const float*)d_in[4];
    const float* rtheta  = (const float*)d_in[5];
    const float* W1      = (const float*)d_in[6];
    const float* b1      = (const float*)d_in[7];
    const float* W2      = (const float*)d_in[8];
    const float* b2      = (const float*)d_in[9];
    float* out = (float*)d_out;
    unsigned* ws = (unsigned*)d_ws;   // needs (4352 + 8N)*4 B  (~280 KB)

    int N = in_sizes[0] / 3;
    int total = N * Lc;

    int pre_blocks = (N + 255) / 256;            // covers N >= 128
    precompute<<<pre_blocks, 256, 0, stream>>>(points, root_rot, lobes, lambdas,
                                               W1, b1, W2, b2, ws, N);
    vis_main<<<(total + 255) / 256, 256, 0, stream>>>(normals, rtheta, ws, out, N);
}

// Round 3
// 26.256 us; speedup vs baseline: 1.0102x; 1.0042x over previous
//
#include <hip/hip_runtime.h>
#include <math.h>

typedef _Float16 h2 __attribute__((ext_vector_type(2)));
typedef __fp16  hh2 __attribute__((ext_vector_type(2)));

constexpr int Lc = 128;
constexpr int Sc = 8;
constexpr int TILES = 4;   // 256-output tiles per block; grid = 1024 blocks = 4/CU

static __device__ __forceinline__ h2 pk(float a, float b) {
    return __builtin_bit_cast(h2, __builtin_amdgcn_cvt_pkrtz(a, b));
}
static __device__ __forceinline__ float fdot2f(h2 a, h2 b, float c) {
#if __has_builtin(__builtin_amdgcn_fdot2)
    return __builtin_amdgcn_fdot2(__builtin_bit_cast(hh2, a),
                                  __builtin_bit_cast(hh2, b), c, false);
#else
    return c + (float)a.x * (float)b.x + (float)a.y * (float)b.y;
#endif
}
static __device__ __forceinline__ float fast_exp2(float x) {
#if __has_builtin(__builtin_amdgcn_exp2f)
    return __builtin_amdgcn_exp2f(x);
#else
    return exp2f(x);
#endif
}

__global__ __launch_bounds__(256, 4) void vis_all(
    const float* __restrict__ points,
    const float* __restrict__ normals,
    const float* __restrict__ root_rot,
    const float* __restrict__ lobes,
    const float* __restrict__ lambdas,
    const float* __restrict__ rtheta,
    const float* __restrict__ W1,
    const float* __restrict__ b1,
    const float* __restrict__ W2,
    const float* __restrict__ b2,
    float* __restrict__ out, int N)
{
    const int tid   = threadIdx.x;
    const int li    = tid & (Lc - 1);
    const int total = N * Lc;
    const int base0 = blockIdx.x * (256 * TILES) + tid;

    // ---- tile-0 rtheta preload: HBM latency hides under the ~500cy prolog ----
    float4 p0 = {0,0,0,0}, p1 = {0,0,0,0};
    if (base0 < total) {
        p0 = *reinterpret_cast<const float4*>(rtheta + (size_t)base0 * Sc);
        p1 = *reinterpret_cast<const float4*>(rtheta + (size_t)base0 * Sc + 4);
    }

    // ================= per-thread lobe record (registers, computed once) ====
    h2 A[8], B[8], D[8], W2h[8];
    float uxs, uys, vxs, vys, vzs, lxc, lyc, lzc, wqp, b2c;
    {
        float lx = lobes[li*3+0], ly = lobes[li*3+1], lz = lobes[li*3+2];
        float inv = 1.0f / (sqrtf(lx*lx + ly*ly + lz*lz) + 1e-6f);
        lx *= inv; ly *= inv; lz *= inv;

        float ux = -ly, uy = lx;                       // cross(z,l)
        inv = 1.0f / (sqrtf(ux*ux + uy*uy) + 1e-6f);
        ux *= inv; uy *= inv;

        float vx = -lz*uy, vy = lz*ux, vz = lx*uy - ly*ux;  // cross(l,U)
        inv = 1.0f / (sqrtf(vx*vx + vy*vy + vz*vz) + 1e-6f);
        vx *= inv; vy *= inv; vz *= inv;

        float sharp = lambdas[li];
        float cp = fmaxf(1.0f - 1.0f/sharp, 0.5f);
        float sp = sqrtf(fmaxf(1.0f - cp*cp, 0.0f));

        uxs = ux*sp; uys = uy*sp;                      // uzs == 0
        vxs = vx*sp; vys = vy*sp; vzs = vz*sp;
        lxc = lx*cp; lyc = ly*cp; lzc = lz*cp;

        const float r0 = root_rot[0], r1 = root_rot[1], r2 = root_rot[2];
        const float r3 = root_rot[3], r4 = root_rot[4], r5 = root_rot[5];
        const float r6 = root_rot[6], r7 = root_rot[7], r8 = root_rot[8];

        float Ur0 = -(uxs*r0 + uys*r3);
        float Ur1 = -(uxs*r1 + uys*r4);
        float Ur2 = -(uxs*r2 + uys*r5);
        float Vr0 = -(vxs*r0 + vys*r3 + vzs*r6);
        float Vr1 = -(vxs*r1 + vys*r4 + vzs*r7);
        float Vr2 = -(vxs*r2 + vys*r5 + vzs*r8);
        float Lr0 = -(lxc*r0 + lyc*r3 + lzc*r6);
        float Lr1 = -(lxc*r1 + lyc*r4 + lzc*r7);
        float Lr2 = -(lxc*r2 + lyc*r5 + lzc*r8);

        #pragma unroll
        for (int k = 0; k < 8; ++k) {
            int h0 = 2*k, h1 = 2*k + 1;
            float a0  = Ur0*W1[48+h0] + Ur1*W1[64+h0] + Ur2*W1[80+h0];
            float a1  = Ur0*W1[48+h1] + Ur1*W1[64+h1] + Ur2*W1[80+h1];
            float bb0 = Vr0*W1[48+h0] + Vr1*W1[64+h0] + Vr2*W1[80+h0];
            float bb1 = Vr0*W1[48+h1] + Vr1*W1[64+h1] + Vr2*W1[80+h1];
            float d0  = Lr0*W1[48+h0] + Lr1*W1[64+h0] + Lr2*W1[80+h0];
            float d1  = Lr0*W1[48+h1] + Lr1*W1[64+h1] + Lr2*W1[80+h1];
            A[k] = pk(a0, a1);
            B[k] = pk(bb0, bb1);
            D[k] = pk(d0, d1);
            W2h[k] = pk(W2[h0], W2[h1]);
        }
        float wq = __expf(sharp * (cp - 1.0f));
        wqp = wq / (8.0f * wq + 1e-6f);
        b2c = -b2[0] * 1.44269504f;
    }

    // ================= per-tile body (256 outputs per tile) =================
    auto tile = [&](int t, float4 q0, float4 q1) {
        const int idx = base0 + t * 256;
        if (idx >= total) return;
        const int n  = idx >> 7;
        const int nu = __builtin_amdgcn_readfirstlane(n);   // wave-uniform

        const float* nn = normals + 3*(size_t)nu;           // s_load path
        float nx = nn[0], ny = nn[1], nz = nn[2];
        const float* pp = points + 3*(size_t)nu;
        float px = pp[0], py = pp[1], pz = pp[2];

        // pb + D -> G (wave-uniform scalar-operand math, replaces precompute)
        h2 G[8];
        #pragma unroll
        for (int k = 0; k < 8; ++k) {
            int h0 = 2*k, h1 = 2*k + 1;
            float v0 = b1[h0] + px*W1[h0] + py*W1[16+h0] + pz*W1[32+h0];
            float v1 = b1[h1] + px*W1[h1] + py*W1[16+h1] + pz*W1[32+h1];
            G[k] = pk(v0, v1) + D[k];
        }

        float rs[Sc] = {q0.x, q0.y, q0.z, q0.w, q1.x, q1.y, q1.z, q1.w};

        // ndot = ct*nU + st*nV + nL
        float nU = nx*uxs + ny*uys;
        float nV = nx*vxs + ny*vys + nz*vzs;
        float nL = nx*lxc + ny*lyc + nz*lzc;

        const h2 zero = {(_Float16)0.0f, (_Float16)0.0f};
        float svis = 0.0f;
        #pragma unroll
        for (int s = 0; s < Sc; ++s) {
            // angle in revolutions; v_sin/cos_f32 take revolutions
            float f  = fmaf(rs[s], 0.125f, (float)s * 0.125f);
            float st = __builtin_amdgcn_sinf(f);
            float ct = __builtin_amdgcn_cosf(f);
            float ndot = fmaf(ct, nU, fmaf(st, nV, nL));

            h2 ct2 = pk(ct, ct);
            h2 st2 = pk(st, st);

            float acc = 0.0f;
            #pragma unroll
            for (int k = 0; k < 8; ++k) {
                h2 hv = __builtin_elementwise_fma(ct2, A[k],
                         __builtin_elementwise_fma(st2, B[k], G[k]));
                hv = __builtin_elementwise_max(hv, zero);
                acc = fdot2f(hv, W2h[k], acc);
            }
            // sigmoid(acc + b2) = 1/(1 + 2^(-(acc+b2)*log2e))
            float e = fast_exp2(fmaf(acc, -1.44269504f, b2c));
            float pred = __builtin_amdgcn_rcpf(1.0f + e);
            svis += (ndot > 1e-6f) ? pred : 0.0f;
        }

        out[idx] = svis * wqp;
    };

    tile(0, p0, p1);
    #pragma unroll 1
    for (int t = 1; t < TILES; ++t) {
        const int idx = base0 + t * 256;
        float4 q0 = {0,0,0,0}, q1 = {0,0,0,0};
        if (idx < total) {
            q0 = *reinterpret_cast<const float4*>(rtheta + (size_t)idx * Sc);
            q1 = *reinterpret_cast<const float4*>(rtheta + (size_t)idx * Sc + 4);
        }
        tile(t, q0, q1);
    }
}

extern "C" void kernel_launch(void* const* d_in, const int* in_sizes, int n_in,
                              void* d_out, int out_size, void* d_ws, size_t ws_size,
                              hipStream_t stream) {
    const float* points  = (const float*)d_in[0];
    const float* normals = (const float*)d_in[1];
    const float* root_rot= (const float*)d_in[2];
    const float* lobes   = (const float*)d_in[3];
    const float* lambdas = (const float*)d_in[4];
    const float* rtheta  = (const float*)d_in[5];
    const float* W1      = (const float*)d_in[6];
    const float* b1      = (const float*)d_in[7];
    const float* W2      = (const float*)d_in[8];
    const float* b2      = (const float*)d_in[9];
    float* out = (float*)d_out;
    (void)d_ws; (void)ws_size;   // no workspace needed

    int N = in_sizes[0] / 3;
    int total = N * Lc;
    int blocks = (total + 256*TILES - 1) / (256*TILES);
    vis_all<<<blocks, 256, 0, stream>>>(points, normals, root_rot, lobes,
                                        lambdas, rtheta, W1, b1, W2, b2, out, N);
}

// Round 4
// 26.015 us; speedup vs baseline: 1.0196x; 1.0093x over previous
//
#include <hip/hip_runtime.h>
#include <math.h>

typedef _Float16 h2 __attribute__((ext_vector_type(2)));
typedef __fp16  hh2 __attribute__((ext_vector_type(2)));

constexpr int Lc = 128;
constexpr int Sc = 8;
// ---- workspace dword map (SoA, coalesced 16B/lane reads) ----
// T[c][li]  c=0..5 : uint4 at dword c*512 + li*4   (A01,A23,B01,B23,D01,D23)
// F0[li]           : float4 at dword 3072 + li*4   (uxs,uys,vxs,vys)
// F1[li]           : float4 at dword 3584 + li*4   (vzs,lxc,lyc,lzc)
// WQP[li]          : float  at dword 4096 + li     ( wq/(8wq+1e-6) )
// W2H              : 8 dwords (half2) at 4224
// B2C              : 1 dword at 4232               ( -b2*log2e )
// PB[n]            : 8 dwords (half2) at 4352+8n
constexpr int F0_OFF = 3072;
constexpr int F1_OFF = 3584;
constexpr int WQ_OFF = 4096;
constexpr int W2_OFF = 4224;
constexpr int B2_OFF = 4232;
constexpr int PB_OFF = 4352;

static __device__ __forceinline__ h2 pk(float a, float b) {
    return __builtin_bit_cast(h2, __builtin_amdgcn_cvt_pkrtz(a, b));
}
static __device__ __forceinline__ h2 u2h(unsigned u) {
    return __builtin_bit_cast(h2, u);
}
static __device__ __forceinline__ unsigned h2u(h2 v) {
    return __builtin_bit_cast(unsigned, v);
}
static __device__ __forceinline__ float fdot2f(h2 a, h2 b, float c) {
#if __has_builtin(__builtin_amdgcn_fdot2)
    return __builtin_amdgcn_fdot2(__builtin_bit_cast(hh2, a),
                                  __builtin_bit_cast(hh2, b), c, false);
#else
    return c + (float)a.x * (float)b.x + (float)a.y * (float)b.y;
#endif
}
static __device__ __forceinline__ float fast_exp2(float x) {
#if __has_builtin(__builtin_amdgcn_exp2f)
    return __builtin_amdgcn_exp2f(x);
#else
    return exp2f(x);
#endif
}

__global__ __launch_bounds__(256) void precompute(
    const float* __restrict__ points,
    const float* __restrict__ root_rot,
    const float* __restrict__ lobes,
    const float* __restrict__ lambdas,
    const float* __restrict__ W1,
    const float* __restrict__ b1,
    const float* __restrict__ W2,
    const float* __restrict__ b2,
    unsigned* __restrict__ ws, int N)
{
    int g = blockIdx.x * 256 + threadIdx.x;

    // ---- per-point pb table: pk(points @ W1[:3] + b1) ----
    if (g < N) {
        float px = points[3*g], py = points[3*g+1], pz = points[3*g+2];
        unsigned* dst = ws + PB_OFF + 8*(size_t)g;
        #pragma unroll
        for (int k = 0; k < 8; ++k) {
            int h0 = 2*k, h1 = 2*k+1;
            float v0 = b1[h0] + px*W1[h0] + py*W1[16+h0] + pz*W1[32+h0];
            float v1 = b1[h1] + px*W1[h1] + py*W1[16+h1] + pz*W1[32+h1];
            dst[k] = h2u(pk(v0, v1));
        }
    }

    // ---- per-lobe SoA records ----
    if (g < Lc) {
        int li = g;
        float lx = lobes[li*3+0], ly = lobes[li*3+1], lz = lobes[li*3+2];
        float inv = 1.0f / (sqrtf(lx*lx + ly*ly + lz*lz) + 1e-6f);
        lx *= inv; ly *= inv; lz *= inv;

        float ux = -ly, uy = lx;                       // cross(z,l)
        inv = 1.0f / (sqrtf(ux*ux + uy*uy) + 1e-6f);
        ux *= inv; uy *= inv;

        float vx = -lz*uy, vy = lz*ux, vz = lx*uy - ly*ux;  // cross(l,U)
        inv = 1.0f / (sqrtf(vx*vx + vy*vy + vz*vz) + 1e-6f);
        vx *= inv; vy *= inv; vz *= inv;

        float sharp = lambdas[li];
        float cp = fmaxf(1.0f - 1.0f/sharp, 0.5f);
        float sp = sqrtf(fmaxf(1.0f - cp*cp, 0.0f));

        float uxs = ux*sp, uys = uy*sp;               // uzs == 0
        float vxs = vx*sp, vys = vy*sp, vzs = vz*sp;
        float lxc = lx*cp, lyc = ly*cp, lzc = lz*cp;

        const float r0 = root_rot[0], r1 = root_rot[1], r2 = root_rot[2];
        const float r3 = root_rot[3], r4 = root_rot[4], r5 = root_rot[5];
        const float r6 = root_rot[6], r7 = root_rot[7], r8 = root_rot[8];

        float Ur0 = -(uxs*r0 + uys*r3);
        float Ur1 = -(uxs*r1 + uys*r4);
        float Ur2 = -(uxs*r2 + uys*r5);
        float Vr0 = -(vxs*r0 + vys*r3 + vzs*r6);
        float Vr1 = -(vxs*r1 + vys*r4 + vzs*r7);
        float Vr2 = -(vxs*r2 + vys*r5 + vzs*r8);
        float Lr0 = -(lxc*r0 + lyc*r3 + lzc*r6);
        float Lr1 = -(lxc*r1 + lyc*r4 + lzc*r7);
        float Lr2 = -(lxc*r2 + lyc*r5 + lzc*r8);

        unsigned abd[24];
        #pragma unroll
        for (int k = 0; k < 8; ++k) {
            int h0 = 2*k, h1 = 2*k + 1;
            float a0 = Ur0*W1[48+h0] + Ur1*W1[64+h0] + Ur2*W1[80+h0];
            float a1 = Ur0*W1[48+h1] + Ur1*W1[64+h1] + Ur2*W1[80+h1];
            float bb0 = Vr0*W1[48+h0] + Vr1*W1[64+h0] + Vr2*W1[80+h0];
            float bb1 = Vr0*W1[48+h1] + Vr1*W1[64+h1] + Vr2*W1[80+h1];
            float d0 = Lr0*W1[48+h0] + Lr1*W1[64+h0] + Lr2*W1[80+h0];
            float d1 = Lr0*W1[48+h1] + Lr1*W1[64+h1] + Lr2*W1[80+h1];
            abd[k]      = h2u(pk(a0, a1));
            abd[8 + k]  = h2u(pk(bb0, bb1));
            abd[16 + k] = h2u(pk(d0, d1));
        }
        uint4* tv = (uint4*)ws;
        #pragma unroll
        for (int c = 0; c < 6; ++c)
            tv[c*128 + li] = *(const uint4*)(abd + 4*c);

        float* wf = (float*)ws;
        *(float4*)(wf + F0_OFF + 4*li) = (float4){uxs, uys, vxs, vys};
        *(float4*)(wf + F1_OFF + 4*li) = (float4){vzs, lxc, lyc, lzc};
        float wq = __expf(sharp * (cp - 1.0f));
        wf[WQ_OFF + li] = wq / (8.0f * wq + 1e-6f);

        if (li == 0) {
            #pragma unroll
            for (int k = 0; k < 8; ++k)
                ws[W2_OFF + k] = h2u(pk(W2[2*k], W2[2*k+1]));
            wf[B2_OFF] = -b2[0] * 1.44269504f;
        }
    }
}

// (256,6): VGPR cap ~85 -> 6 waves/SIMD (was 4 at cap 128). Unroll-4 keeps
// 4 independent dot-chains of ILP while dropping live VGPRs to ~70 so the
// 85-reg budget holds without spills. This is the occupancy probe: if the
// kernel is wave-start-stall bound, +50% TLP converts idle waitcnt cycles
// into issue cycles.
__global__ __launch_bounds__(256, 6) void vis_main(
    const float* __restrict__ normals,  // N,3
    const float* __restrict__ rtheta,   // N,L,S
    const unsigned* __restrict__ ws,
    float* __restrict__ out, int N)
{
    int idx = blockIdx.x * 256 + threadIdx.x;
    if (idx >= N * Lc) return;
    int n  = idx >> 7;
    int li = idx & (Lc - 1);

    // ---- per-lobe SoA reads: 16B/lane, coalesced, L1/L2-hot ----
    const uint4* tv = (const uint4*)ws;
    uint4 a01 = tv[0*128 + li];
    uint4 a23 = tv[1*128 + li];
    uint4 bb01 = tv[2*128 + li];
    uint4 bb23 = tv[3*128 + li];
    uint4 d01 = tv[4*128 + li];
    uint4 d23 = tv[5*128 + li];
    const float* wf = (const float*)ws;
    float4 f0 = *(const float4*)(wf + F0_OFF + 4*li);
    float4 f1 = *(const float4*)(wf + F1_OFF + 4*li);
    float wqp = wf[WQ_OFF + li];

    // ---- rtheta: 32 B/lane coalesced ----
    const float4 q0 = *reinterpret_cast<const float4*>(rtheta + (size_t)idx * Sc);
    const float4 q1 = *reinterpret_cast<const float4*>(rtheta + (size_t)idx * Sc + 4);
    float rs[Sc] = {q0.x, q0.y, q0.z, q0.w, q1.x, q1.y, q1.z, q1.w};

    // ---- wave-uniform per-point data (scalar path) ----
    int nu = __builtin_amdgcn_readfirstlane(n);
    const float* nn = normals + 3*(size_t)nu;
    float nx = nn[0], ny = nn[1], nz = nn[2];
    const unsigned* pbp = ws + PB_OFF + 8*(size_t)nu;
    unsigned pb[8] = {pbp[0], pbp[1], pbp[2], pbp[3],
                      pbp[4], pbp[5], pbp[6], pbp[7]};

    h2 A[8] = {u2h(a01.x), u2h(a01.y), u2h(a01.z), u2h(a01.w),
               u2h(a23.x), u2h(a23.y), u2h(a23.z), u2h(a23.w)};
    h2 B[8] = {u2h(bb01.x), u2h(bb01.y), u2h(bb01.z), u2h(bb01.w),
               u2h(bb23.x), u2h(bb23.y), u2h(bb23.z), u2h(bb23.w)};
    h2 G[8] = {u2h(pb[0]) + u2h(d01.x), u2h(pb[1]) + u2h(d01.y),
               u2h(pb[2]) + u2h(d01.z), u2h(pb[3]) + u2h(d01.w),
               u2h(pb[4]) + u2h(d23.x), u2h(pb[5]) + u2h(d23.y),
               u2h(pb[6]) + u2h(d23.z), u2h(pb[7]) + u2h(d23.w)};
    h2 W2h[8] = {u2h(ws[W2_OFF+0]), u2h(ws[W2_OFF+1]),
                 u2h(ws[W2_OFF+2]), u2h(ws[W2_OFF+3]),
                 u2h(ws[W2_OFF+4]), u2h(ws[W2_OFF+5]),
                 u2h(ws[W2_OFF+6]), u2h(ws[W2_OFF+7])};
    float b2c = wf[B2_OFF];   // -b2*log2e

    // ndot = ct*nU + st*nV + nL
    float nU = nx*f0.x + ny*f0.y;
    float nV = nx*f0.z + ny*f0.w + nz*f1.x;
    float nL = nx*f1.y + ny*f1.z + nz*f1.w;

    const h2 zero = {(_Float16)0.0f, (_Float16)0.0f};
    float svis = 0.0f;
    #pragma unroll 4
    for (int s = 0; s < Sc; ++s) {
        // angle in revolutions; v_sin/cos_f32 take revolutions
        float f  = fmaf(rs[s], 0.125f, (float)s * 0.125f);
        float st = __builtin_amdgcn_sinf(f);
        float ct = __builtin_amdgcn_cosf(f);
        float ndot = fmaf(ct, nU, fmaf(st, nV, nL));

        h2 ct2 = pk(ct, ct);
        h2 st2 = pk(st, st);

        float acc = 0.0f;
        #pragma unroll
        for (int k = 0; k < 8; ++k) {
            h2 hv = __builtin_elementwise_fma(ct2, A[k],
                     __builtin_elementwise_fma(st2, B[k], G[k]));
            hv = __builtin_elementwise_max(hv, zero);
            acc = fdot2f(hv, W2h[k], acc);
        }
        // sigmoid(acc + b2) = 1/(1 + 2^(-(acc+b2)*log2e))
        float e = fast_exp2(fmaf(acc, -1.44269504f, b2c));
        float pred = __builtin_amdgcn_rcpf(1.0f + e);
        svis += (ndot > 1e-6f) ? pred : 0.0f;
    }

    out[idx] = svis * wqp;
}

extern "C" void kernel_launch(void* const* d_in, const int* in_sizes, int n_in,
                              void* d_out, int out_size, void* d_ws, size_t ws_size,
                              hipStream_t stream) {
    const float* points  = (const float*)d_in[0];
    const float* normals = (const float*)d_in[1];
    const float* root_rot= (const float*)d_in[2];
    const float* lobes   = (const float*)d_in[3];
    const float* lambdas = (const float*)d_in[4];
    const float* rtheta  = (const float*)d_in[5];
    const float* W1      = (const float*)d_in[6];
    const float* b1      = (const float*)d_in[7];
    const float* W2      = (const float*)d_in[8];
    const float* b2      = (const float*)d_in[9];
    float* out = (float*)d_out;
    unsigned* ws = (unsigned*)d_ws;   // needs (4352 + 8N)*4 B  (~280 KB)

    int N = in_sizes[0] / 3;
    int total = N * Lc;

    int pre_blocks = (N + 255) / 256;            // covers N >= 128
    precompute<<<pre_blocks, 256, 0, stream>>>(points, root_rot, lobes, lambdas,
                                               W1, b1, W2, b2, ws, N);
    vis_main<<<(total + 255) / 256, 256, 0, stream>>>(normals, rtheta, ws, out, N);
}

// Round 5
// 24.476 us; speedup vs baseline: 1.0837x; 1.0629x over previous
//
#include <hip/hip_runtime.h>
#include <math.h>

typedef _Float16 h2 __attribute__((ext_vector_type(2)));
typedef __fp16  hh2 __attribute__((ext_vector_type(2)));

constexpr int Lc = 128;
constexpr int Sc = 8;
// ---- workspace dword map (SoA, coalesced 16B/lane reads) ----
// T[c][li]  c=0..5 : uint4 at dword c*512 + li*4   (A01,A23,B01,B23,D01,D23)
// F0[li]           : float4 at dword 3072 + li*4   (uxs,uys,vxs,vys)
// F1[li]           : float4 at dword 3584 + li*4   (vzs,lxc,lyc,lzc)
// WQP[li]          : float  at dword 4096 + li     ( wq/(8wq+1e-6) )
// W2H              : 8 dwords (half2) at 4224
// B2C              : 1 dword at 4232               ( -b2*log2e )
// PB[n]            : 8 dwords (half2) at 4352+8n
constexpr int F0_OFF = 3072;
constexpr int F1_OFF = 3584;
constexpr int WQ_OFF = 4096;
constexpr int W2_OFF = 4224;
constexpr int B2_OFF = 4232;
constexpr int PB_OFF = 4352;

// Evidence ledger (sessions r0-r4): 2-dispatch + full-unroll + 4 waves/SIMD
// is the proven optimum of this structure family:
//   r0 24.88 (this structure) | r1 fused-LDS 26.52 | r2 unroll-2 26.37
//   r3 persistent 26.26 | r4 occ-6/unroll-4 26.01
// ILP (8 independent dot-chains) is load-bearing; extra occupancy is not;
// dispatch-count reduction never paid. Only remaining in-kernel lever:
// issue the HBM rtheta loads BEFORE the L1/L2-hot ws loads.

static __device__ __forceinline__ h2 pk(float a, float b) {
    return __builtin_bit_cast(h2, __builtin_amdgcn_cvt_pkrtz(a, b));
}
static __device__ __forceinline__ h2 u2h(unsigned u) {
    return __builtin_bit_cast(h2, u);
}
static __device__ __forceinline__ unsigned h2u(h2 v) {
    return __builtin_bit_cast(unsigned, v);
}
static __device__ __forceinline__ float fdot2f(h2 a, h2 b, float c) {
#if __has_builtin(__builtin_amdgcn_fdot2)
    return __builtin_amdgcn_fdot2(__builtin_bit_cast(hh2, a),
                                  __builtin_bit_cast(hh2, b), c, false);
#else
    return c + (float)a.x * (float)b.x + (float)a.y * (float)b.y;
#endif
}
static __device__ __forceinline__ float fast_exp2(float x) {
#if __has_builtin(__builtin_amdgcn_exp2f)
    return __builtin_amdgcn_exp2f(x);
#else
    return exp2f(x);
#endif
}

__global__ __launch_bounds__(256) void precompute(
    const float* __restrict__ points,
    const float* __restrict__ root_rot,
    const float* __restrict__ lobes,
    const float* __restrict__ lambdas,
    const float* __restrict__ W1,
    const float* __restrict__ b1,
    const float* __restrict__ W2,
    const float* __restrict__ b2,
    unsigned* __restrict__ ws, int N)
{
    int g = blockIdx.x * 256 + threadIdx.x;

    // ---- per-point pb table: pk(points @ W1[:3] + b1) ----
    if (g < N) {
        float px = points[3*g], py = points[3*g+1], pz = points[3*g+2];
        unsigned* dst = ws + PB_OFF + 8*(size_t)g;
        #pragma unroll
        for (int k = 0; k < 8; ++k) {
            int h0 = 2*k, h1 = 2*k+1;
            float v0 = b1[h0] + px*W1[h0] + py*W1[16+h0] + pz*W1[32+h0];
            float v1 = b1[h1] + px*W1[h1] + py*W1[16+h1] + pz*W1[32+h1];
            dst[k] = h2u(pk(v0, v1));
        }
    }

    // ---- per-lobe SoA records ----
    if (g < Lc) {
        int li = g;
        float lx = lobes[li*3+0], ly = lobes[li*3+1], lz = lobes[li*3+2];
        float inv = 1.0f / (sqrtf(lx*lx + ly*ly + lz*lz) + 1e-6f);
        lx *= inv; ly *= inv; lz *= inv;

        float ux = -ly, uy = lx;                       // cross(z,l)
        inv = 1.0f / (sqrtf(ux*ux + uy*uy) + 1e-6f);
        ux *= inv; uy *= inv;

        float vx = -lz*uy, vy = lz*ux, vz = lx*uy - ly*ux;  // cross(l,U)
        inv = 1.0f / (sqrtf(vx*vx + vy*vy + vz*vz) + 1e-6f);
        vx *= inv; vy *= inv; vz *= inv;

        float sharp = lambdas[li];
        float cp = fmaxf(1.0f - 1.0f/sharp, 0.5f);
        float sp = sqrtf(fmaxf(1.0f - cp*cp, 0.0f));

        float uxs = ux*sp, uys = uy*sp;               // uzs == 0
        float vxs = vx*sp, vys = vy*sp, vzs = vz*sp;
        float lxc = lx*cp, lyc = ly*cp, lzc = lz*cp;

        const float r0 = root_rot[0], r1 = root_rot[1], r2 = root_rot[2];
        const float r3 = root_rot[3], r4 = root_rot[4], r5 = root_rot[5];
        const float r6 = root_rot[6], r7 = root_rot[7], r8 = root_rot[8];

        float Ur0 = -(uxs*r0 + uys*r3);
        float Ur1 = -(uxs*r1 + uys*r4);
        float Ur2 = -(uxs*r2 + uys*r5);
        float Vr0 = -(vxs*r0 + vys*r3 + vzs*r6);
        float Vr1 = -(vxs*r1 + vys*r4 + vzs*r7);
        float Vr2 = -(vxs*r2 + vys*r5 + vzs*r8);
        float Lr0 = -(lxc*r0 + lyc*r3 + lzc*r6);
        float Lr1 = -(lxc*r1 + lyc*r4 + lzc*r7);
        float Lr2 = -(lxc*r2 + lyc*r5 + lzc*r8);

        unsigned abd[24];
        #pragma unroll
        for (int k = 0; k < 8; ++k) {
            int h0 = 2*k, h1 = 2*k + 1;
            float a0 = Ur0*W1[48+h0] + Ur1*W1[64+h0] + Ur2*W1[80+h0];
            float a1 = Ur0*W1[48+h1] + Ur1*W1[64+h1] + Ur2*W1[80+h1];
            float bb0 = Vr0*W1[48+h0] + Vr1*W1[64+h0] + Vr2*W1[80+h0];
            float bb1 = Vr0*W1[48+h1] + Vr1*W1[64+h1] + Vr2*W1[80+h1];
            float d0 = Lr0*W1[48+h0] + Lr1*W1[64+h0] + Lr2*W1[80+h0];
            float d1 = Lr0*W1[48+h1] + Lr1*W1[64+h1] + Lr2*W1[80+h1];
            abd[k]      = h2u(pk(a0, a1));
            abd[8 + k]  = h2u(pk(bb0, bb1));
            abd[16 + k] = h2u(pk(d0, d1));
        }
        uint4* tv = (uint4*)ws;
        #pragma unroll
        for (int c = 0; c < 6; ++c)
            tv[c*128 + li] = *(const uint4*)(abd + 4*c);

        float* wf = (float*)ws;
        *(float4*)(wf + F0_OFF + 4*li) = (float4){uxs, uys, vxs, vys};
        *(float4*)(wf + F1_OFF + 4*li) = (float4){vzs, lxc, lyc, lzc};
        float wq = __expf(sharp * (cp - 1.0f));
        wf[WQ_OFF + li] = wq / (8.0f * wq + 1e-6f);

        if (li == 0) {
            #pragma unroll
            for (int k = 0; k < 8; ++k)
                ws[W2_OFF + k] = h2u(pk(W2[2*k], W2[2*k+1]));
            wf[B2_OFF] = -b2[0] * 1.44269504f;
        }
    }
}

__global__ __launch_bounds__(256, 4) void vis_main(
    const float* __restrict__ normals,  // N,3
    const float* __restrict__ rtheta,   // N,L,S
    const unsigned* __restrict__ ws,
    float* __restrict__ out, int N)
{
    int idx = blockIdx.x * 256 + threadIdx.x;
    if (idx >= N * Lc) return;
    int n  = idx >> 7;
    int li = idx & (Lc - 1);

    // ---- rtheta FIRST: the only HBM-latency loads in the kernel; issue
    //      them before the L1/L2-hot ws reads so their ~900cy miss hides
    //      under the ws loads + G/ndot setup VALU ----
    const float4 q0 = *reinterpret_cast<const float4*>(rtheta + (size_t)idx * Sc);
    const float4 q1 = *reinterpret_cast<const float4*>(rtheta + (size_t)idx * Sc + 4);

    // ---- wave-uniform per-point data (scalar path) ----
    int nu = __builtin_amdgcn_readfirstlane(n);
    const float* nn = normals + 3*(size_t)nu;
    float nx = nn[0], ny = nn[1], nz = nn[2];
    const unsigned* pbp = ws + PB_OFF + 8*(size_t)nu;
    unsigned pb[8] = {pbp[0], pbp[1], pbp[2], pbp[3],
                      pbp[4], pbp[5], pbp[6], pbp[7]};

    // ---- per-lobe SoA reads: 16B/lane, coalesced, L1/L2-hot ----
    const uint4* tv = (const uint4*)ws;
    uint4 a01 = tv[0*128 + li];
    uint4 a23 = tv[1*128 + li];
    uint4 bb01 = tv[2*128 + li];
    uint4 bb23 = tv[3*128 + li];
    uint4 d01 = tv[4*128 + li];
    uint4 d23 = tv[5*128 + li];
    const float* wf = (const float*)ws;
    float4 f0 = *(const float4*)(wf + F0_OFF + 4*li);
    float4 f1 = *(const float4*)(wf + F1_OFF + 4*li);
    float wqp = wf[WQ_OFF + li];

    h2 A[8] = {u2h(a01.x), u2h(a01.y), u2h(a01.z), u2h(a01.w),
               u2h(a23.x), u2h(a23.y), u2h(a23.z), u2h(a23.w)};
    h2 B[8] = {u2h(bb01.x), u2h(bb01.y), u2h(bb01.z), u2h(bb01.w),
               u2h(bb23.x), u2h(bb23.y), u2h(bb23.z), u2h(bb23.w)};
    h2 G[8] = {u2h(pb[0]) + u2h(d01.x), u2h(pb[1]) + u2h(d01.y),
               u2h(pb[2]) + u2h(d01.z), u2h(pb[3]) + u2h(d01.w),
               u2h(pb[4]) + u2h(d23.x), u2h(pb[5]) + u2h(d23.y),
               u2h(pb[6]) + u2h(d23.z), u2h(pb[7]) + u2h(d23.w)};
    h2 W2h[8] = {u2h(ws[W2_OFF+0]), u2h(ws[W2_OFF+1]),
                 u2h(ws[W2_OFF+2]), u2h(ws[W2_OFF+3]),
                 u2h(ws[W2_OFF+4]), u2h(ws[W2_OFF+5]),
                 u2h(ws[W2_OFF+6]), u2h(ws[W2_OFF+7])};
    float b2c = wf[B2_OFF];   // -b2*log2e

    // ndot = ct*nU + st*nV + nL
    float nU = nx*f0.x + ny*f0.y;
    float nV = nx*f0.z + ny*f0.w + nz*f1.x;
    float nL = nx*f1.y + ny*f1.z + nz*f1.w;

    float rs[Sc] = {q0.x, q0.y, q0.z, q0.w, q1.x, q1.y, q1.z, q1.w};

    const h2 zero = {(_Float16)0.0f, (_Float16)0.0f};
    float svis = 0.0f;
    // full unroll: 8 independent dot-chains of ILP — proven load-bearing
    // (unroll-2: +1.5us, unroll-4: +1.1us vs full).
    #pragma unroll
    for (int s = 0; s < Sc; ++s) {
        // angle in revolutions; v_sin/cos_f32 take revolutions
        float f  = fmaf(rs[s], 0.125f, (float)s * 0.125f);
        float st = __builtin_amdgcn_sinf(f);
        float ct = __builtin_amdgcn_cosf(f);
        float ndot = fmaf(ct, nU, fmaf(st, nV, nL));

        h2 ct2 = pk(ct, ct);
        h2 st2 = pk(st, st);

        float acc = 0.0f;
        #pragma unroll
        for (int k = 0; k < 8; ++k) {
            h2 hv = __builtin_elementwise_fma(ct2, A[k],
                     __builtin_elementwise_fma(st2, B[k], G[k]));
            hv = __builtin_elementwise_max(hv, zero);
            acc = fdot2f(hv, W2h[k], acc);
        }
        // sigmoid(acc + b2) = 1/(1 + 2^(-(acc+b2)*log2e))
        float e = fast_exp2(fmaf(acc, -1.44269504f, b2c));
        float pred = __builtin_amdgcn_rcpf(1.0f + e);
        svis += (ndot > 1e-6f) ? pred : 0.0f;
    }

    out[idx] = svis * wqp;
}

extern "C" void kernel_launch(void* const* d_in, const int* in_sizes, int n_in,
                              void* d_out, int out_size, void* d_ws, size_t ws_size,
                              hipStream_t stream) {
    const float* points  = (const float*)d_in[0];
    const float* normals = (const float*)d_in[1];
    const float* root_rot= (const float*)d_in[2];
    const float* lobes   = (const float*)d_in[3];
    const float* lambdas = (const float*)d_in[4];
    const float* rtheta  = (const float*)d_in[5];
    const float* W1      = (const float*)d_in[6];
    const float* b1      = (const float*)d_in[7];
    const float* W2      = (const float*)d_in[8];
    const float* b2      = (const float*)d_in[9];
    float* out = (float*)d_out;
    unsigned* ws = (unsigned*)d_ws;   // needs (4352 + 8N)*4 B  (~280 KB)

    int N = in_sizes[0] / 3;
    int total = N * Lc;

    int pre_blocks = (N + 255) / 256;            // covers N >= 128
    precompute<<<pre_blocks, 256, 0, stream>>>(points, root_rot, lobes, lambdas,
                                               W1, b1, W2, b2, ws, N);
    vis_main<<<(total + 255) / 256, 256, 0, stream>>>(normals, rtheta, ws, out, N);
}